// Round 15
// baseline (176.295 us; speedup 1.0000x reference)
//
#include <hip/hip_runtime.h>
#include <hip/hip_bf16.h>
#include <math.h>
#include <stdint.h>

#define DIM 300
#define NC 256
#define KS 3
#define NCLASS 3
#define BB 128
#define L1 512
#define L2 32

#define XW 352            // Xc row: [emb 0..299 | 0 300..319 | alpha 320..351]
#define XROWS 514         // guard row + 512 + guard row, per batch
#define ROW_B (XW * 2)    // 704 bytes = 11 x 64B chunks
#define NKC 11            // conv K-chunks (kc 0..9 static, kc 10 = alpha x G)
#define WP2_ELEMS (2 * 4 * 10 * 3 * 4 * 64 * 8)   // 491,520 conv B-frags (32x32 layout)
#define WB_ELEMS (10 * 19 * 64 * 8)               // 97,280: W for sx/sy
#define WG2_ELEMS (3 * 10 * 16 * 64 * 8)          // 245,760: w2 B-frags for G
#define GT_ELEMS (BB * 3 * 32 * 256)              // 3,145,728 plain G
#define GATH_ELEMS (BB * L2 * 320)                // 1,310,720 aspect gather
#define WAVE_WP_B (10 * 3 * 2 * 2 * 1024)         // 122,880 B per (cb,role)
#define PREP_BLOCKS ((WP2_ELEMS + WB_ELEMS + WG2_ELEMS + GATH_ELEMS) / 256)  // 8380
#define XCAT_BLOCKS (BB * L1 / 8)                 // 8192

#define ABUF_B 4224       // one A buffer (66 rows x 64B)
#define EP_LD1 260        // epilogue stride (floats), 256 cols + pad

typedef __attribute__((ext_vector_type(8))) short bf16x8;
typedef __attribute__((ext_vector_type(4))) short bf16x4;
typedef __attribute__((ext_vector_type(4))) float f32x4;
typedef __attribute__((ext_vector_type(16))) float f32x16;

#define GLOBAL_AS __attribute__((address_space(1)))
#define LDS_AS __attribute__((address_space(3)))

__device__ __forceinline__ void gload_lds16(const void* g, void* l) {
    __builtin_amdgcn_global_load_lds((const GLOBAL_AS void*)g, (LDS_AS void*)l, 16, 0, 0);
}

static __device__ __forceinline__ short bfr(float x) {
    __hip_bfloat16 h = __float2bfloat16(x);
    return *(short*)&h;
}

// ---------------- one flat prep kernel: conv B-frags (32x32 MFMA layout) |
// W B-frags | w2 B-frags | aspect gather | (blocks >= PREP_BLOCKS) Xcat gather
__global__ void prep_all(const float* __restrict__ ctx_w,
                         const float* __restrict__ gate_w,
                         const float* __restrict__ Wm,
                         const int* __restrict__ aids,
                         const int* __restrict__ cids,
                         const float* __restrict__ wordmat,
                         __hip_bfloat16* __restrict__ Wp2,
                         __hip_bfloat16* __restrict__ Wb,
                         __hip_bfloat16* __restrict__ Wg2,
                         __hip_bfloat16* __restrict__ aspb,
                         __hip_bfloat16* __restrict__ syb,
                         __hip_bfloat16* __restrict__ Xc) {
    if (blockIdx.x >= PREP_BLOCKS) {
        int xb = blockIdx.x - PREP_BLOCKS;
        int t = threadIdx.x;
        int rloc = t >> 5, lane = t & 31;
        int row = xb * 8 + rloc;                  // 0..65535
        int b = row >> 9, l = row & 511;
        size_t id = (size_t)cids[row];
        const float4* src = (const float4*)(wordmat + id * DIM);
        __hip_bfloat16* dst = Xc + ((size_t)b * XROWS + 1 + l) * XW;
        #pragma unroll
        for (int c = lane; c < 80; c += 32) {     // cols 0..319 (alpha written later)
            bf16x4 o;
            if (c < 75) {
                float4 f = src[c];
                o[0] = bfr(f.x); o[1] = bfr(f.y); o[2] = bfr(f.z); o[3] = bfr(f.w);
            } else {
                o = (bf16x4)0;   // cols 300..319
            }
            ((bf16x4*)dst)[c] = o;
        }
        if (xb < 256 && t < 88) {                 // zero guard rows
            int b2 = xb >> 1;
            int gr = (xb & 1) ? (XROWS - 1) : 0;
            ((bf16x4*)(Xc + ((size_t)b2 * XROWS + gr) * XW))[t] = (bf16x4)0;
        }
        return;
    }
    int idx = blockIdx.x * 256 + threadIdx.x;
    if (idx < WP2_ELEMS) {
        // Wp2[cb][role][kc][tap][nt][kh][lane][8] for mfma_32x32x16:
        // B elem: k = kc*32 + kh*16 + (lane>>5)*8 + jj ; col = nt*32 + (lane&31)
        int jj = idx & 7;
        int lane = (idx >> 3) & 63;
        int kh = (idx >> 9) & 1;
        int nt = (idx >> 10) & 1;
        int rest = idx >> 11;
        int tap = rest % 3;
        int r2 = rest / 3;
        int kc = r2 % 10;
        int w = r2 / 10;
        int role = w & 3, cbv = w >> 2;
        int k = kc * 32 + kh * 16 + ((lane >> 5) << 3) + jj;
        int nl = role * 64 + nt * 32 + (lane & 31);
        float v = 0.f;
        if (nl < 128) {
            int ch = cbv * 128 + nl;
            if (k < 300) v = ctx_w[(ch * DIM + k) * KS + tap];
        } else {
            int ch = cbv * 128 + (nl - 128);
            if (k < 300) v = gate_w[(ch * 2 * DIM + k) * KS + tap];
        }
        Wp2[idx] = __float2bfloat16(v);
        return;
    }
    idx -= WP2_ELEMS;
    if (idx < WB_ELEMS) {
        int j = idx & 7;
        int l = (idx >> 3) & 63;
        int r = idx >> 9;
        int nf = r % 19, kc = r / 19;
        int k = kc * 32 + ((l >> 4) << 3) + j;
        int n = nf * 16 + (l & 15);
        float v = (k < 300 && n < 300) ? Wm[k * DIM + n] : 0.f;
        Wb[idx] = __float2bfloat16(v);
        return;
    }
    idx -= WB_ELEMS;
    if (idx < WG2_ELEMS) {
        int jj = idx & 7;
        int lane = (idx >> 3) & 63;
        int rest = idx >> 9;
        int nf = rest % 16;
        int r2 = rest / 16;
        int kc = r2 % 10, tap = r2 / 10;
        int k = kc * 32 + ((lane >> 4) << 3) + jj;
        int n = nf * 16 + (lane & 15);
        float v = (k < 300) ? gate_w[(n * 2 * DIM + DIM + k) * KS + tap] : 0.f;
        Wg2[idx] = __float2bfloat16(v);
        return;
    }
    idx -= WG2_ELEMS;
    if (idx < GATH_ELEMS) {
        int row = idx / 320, d = idx - row * 320;
        if (d < DIM) {
            aspb[(size_t)row * 320 + d] = __float2bfloat16(wordmat[(size_t)aids[row] * DIM + d]);
        } else {
            aspb[(size_t)row * 320 + d] = __float2bfloat16(0.f);
            if (d >= 304) syb[(size_t)row * 320 + d] = __float2bfloat16(0.f);
        }
    }
}

// ---------------- merged aspect MFMA: sy = relu(aspect@W) [blocks 0..63]
//                  and G[b,tap] = aspect[b] @ w2^T [blocks 64..447]
__global__ __launch_bounds__(256, 2) void asp_mfma(
        const __hip_bfloat16* __restrict__ aspb,
        const __hip_bfloat16* __restrict__ Wb,
        const __hip_bfloat16* __restrict__ Wg2,
        __hip_bfloat16* __restrict__ syb,
        __hip_bfloat16* __restrict__ Gt) {
    const int t = threadIdx.x, wave = t >> 6, l = t & 63;
    const int lane15 = l & 15, lq = l >> 4;
    if (blockIdx.x < 64) {
        const int g = blockIdx.x * 64 + wave * 16 + lane15;
        f32x4 acc[19];
        #pragma unroll
        for (int nf = 0; nf < 19; ++nf) acc[nf] = (f32x4)0.f;
        const bf16x8* Arow = (const bf16x8*)((const char*)aspb + (size_t)g * 640);
        const bf16x8* WbV = (const bf16x8*)Wb;
        for (int kc = 0; kc < 10; ++kc) {
            bf16x8 af = Arow[kc * 4 + lq];
            #pragma unroll
            for (int nf = 0; nf < 19; ++nf)
                acc[nf] = __builtin_amdgcn_mfma_f32_16x16x32_bf16(
                    af, WbV[(kc * 19 + nf) * 64 + l], acc[nf], 0, 0, 0);
        }
        #pragma unroll
        for (int nf = 0; nf < 19; ++nf) {
            int col = nf * 16 + lane15;
            #pragma unroll
            for (int i2 = 0; i2 < 4; ++i2) {
                int row = blockIdx.x * 64 + wave * 16 + lq * 4 + i2;
                syb[(size_t)row * 320 + col] = __float2bfloat16(fmaxf(acc[nf][i2], 0.f));
            }
        }
    } else {
        const int i = blockIdx.x - 64;
        const int b = i / 3, tap = i - b * 3;
        f32x4 acc[2][4];
        #pragma unroll
        for (int m = 0; m < 2; ++m)
            #pragma unroll
            for (int ni = 0; ni < 4; ++ni) acc[m][ni] = (f32x4)0.f;
        const char* Ab = (const char*)aspb + (size_t)b * 32 * 640;
        const bf16x8* WgV = (const bf16x8*)Wg2;
        for (int kc = 0; kc < 10; ++kc) {
            bf16x8 af[2];
            #pragma unroll
            for (int m = 0; m < 2; ++m)
                af[m] = *(const bf16x8*)(Ab + (size_t)(m * 16 + lane15) * 640 + kc * 64 + lq * 16);
            #pragma unroll
            for (int ni = 0; ni < 4; ++ni) {
                bf16x8 bw = WgV[((size_t)(tap * 10 + kc) * 16 + wave * 4 + ni) * 64 + l];
                #pragma unroll
                for (int m = 0; m < 2; ++m)
                    acc[m][ni] = __builtin_amdgcn_mfma_f32_16x16x32_bf16(af[m], bw, acc[m][ni], 0, 0, 0);
            }
        }
        #pragma unroll
        for (int m = 0; m < 2; ++m)
            #pragma unroll
            for (int ni = 0; ni < 4; ++ni) {
                int c = (wave * 4 + ni) * 16 + lane15;
                #pragma unroll
                for (int i2 = 0; i2 < 4; ++i2) {
                    int j = m * 16 + lq * 4 + i2;
                    Gt[((size_t)(b * 3 + tap) * 32 + j) * 256 + c] = __float2bfloat16(acc[m][ni][i2]);
                }
            }
    }
}

// ---------------- fused sx+s: 64 rows/block, T1 bijective XCD swizzle
__global__ __launch_bounds__(256, 2) void sxs_mfma(
        const __hip_bfloat16* __restrict__ Xc,
        const __hip_bfloat16* __restrict__ Wb,
        const __hip_bfloat16* __restrict__ syb,
        float* __restrict__ s) {
    __shared__ __align__(16) char sxL[4 * 16 * 640];  // 40KB, wave-private
    const int t = threadIdx.x, wave = t >> 6, l = t & 63;
    const int lane15 = l & 15, lq = l >> 4;
    const int flat = blockIdx.y * 8 + blockIdx.x;
    const int wf = (flat & 7) * 128 + (flat >> 3);
    const int lb = wf & 7, b = wf >> 3;
    const int g = b * XROWS + 1 + lb * 64 + wave * 16 + lane15;

    f32x4 acc[19];
    #pragma unroll
    for (int nf = 0; nf < 19; ++nf) acc[nf] = (f32x4)0.f;

    const bf16x8* Arow = (const bf16x8*)((const char*)Xc + (size_t)g * ROW_B);
    const bf16x8* WbV = (const bf16x8*)Wb;
    for (int kc = 0; kc < 10; ++kc) {
        bf16x8 af = Arow[kc * 4 + lq];
        #pragma unroll
        for (int nf = 0; nf < 19; ++nf)
            acc[nf] = __builtin_amdgcn_mfma_f32_16x16x32_bf16(
                af, WbV[(kc * 19 + nf) * 64 + l], acc[nf], 0, 0, 0);
    }

    char* sxW = sxL + wave * (16 * 640);
    if (l < 32) {
        int row = l >> 1;
        int phys = (2 + (l & 1)) ^ ((row >> 2) & 3);
        *(f32x4*)(sxW + row * 640 + 576 + phys * 16) = (f32x4)0.f;
    }
    #pragma unroll
    for (int nf = 0; nf < 19; ++nf) {
        int col = nf * 16 + lane15;
        #pragma unroll
        for (int i2 = 0; i2 < 4; ++i2) {
            int row = lq * 4 + i2;
            int off = row * 640 + ((col >> 5) << 6) +
                      ((((col >> 3) & 3) ^ ((row >> 2) & 3)) << 4) + ((col & 7) << 1);
            *(__hip_bfloat16*)(sxW + off) = __float2bfloat16(fmaxf(acc[nf][i2], 0.f));
        }
    }
    f32x4 acc2[2];
    acc2[0] = (f32x4)0.f;
    acc2[1] = (f32x4)0.f;
    const bf16x8* syV = (const bf16x8*)syb + (size_t)b * 32 * 40;
    for (int kc = 0; kc < 10; ++kc) {
        bf16x8 af2 = *(const bf16x8*)(sxW + lane15 * 640 + kc * 64 +
                                      ((lq ^ ((lane15 >> 2) & 3)) << 4));
        #pragma unroll
        for (int nj = 0; nj < 2; ++nj) {
            bf16x8 bfj = syV[(nj * 16 + lane15) * 40 + kc * 4 + lq];
            acc2[nj] = __builtin_amdgcn_mfma_f32_16x16x32_bf16(af2, bfj, acc2[nj], 0, 0, 0);
        }
    }
    #pragma unroll
    for (int nj = 0; nj < 2; ++nj)
        #pragma unroll
        for (int i2 = 0; i2 < 4; ++i2) {
            int i = lb * 64 + wave * 16 + lq * 4 + i2;
            s[((size_t)b * L1 + i) * L2 + nj * 16 + lane15] = acc2[nj][i2];
        }
}

// ---------------- softmax over dim=1 (L1): bf16 alpha straight into Xc[320..351]
__global__ __launch_bounds__(256) void softmax_col(const float* __restrict__ s,
                                                   const float* __restrict__ amask,
                                                   __hip_bfloat16* __restrict__ Xc) {
    __shared__ float red[256];
    __shared__ float cmax[8], cscale[8];
    int b = blockIdx.x, jh = blockIdx.y, t = threadIdx.x;
    int jl = t & 7, j = jh * 8 + jl, ii = t >> 3;
    const float* sb = s + (size_t)b * L1 * L2;
    float v[16];
    float m = -1e30f;
    #pragma unroll
    for (int q = 0; q < 16; ++q) {
        v[q] = sb[(size_t)(ii + q * 32) * L2 + j];
        m = fmaxf(m, v[q]);
    }
    red[t] = m;
    __syncthreads();
    if (t < 8) {
        float mm = red[t];
        for (int p = 1; p < 32; ++p) mm = fmaxf(mm, red[p * 8 + t]);
        cmax[t] = mm;
    }
    __syncthreads();
    float cm = cmax[jl];
    float sum = 0.f;
    #pragma unroll
    for (int q = 0; q < 16; ++q) {
        v[q] = expf(v[q] - cm);
        sum += v[q];
    }
    red[t] = sum;
    __syncthreads();
    if (t < 8) {
        float ss = 0.f;
        for (int p = 0; p < 32; ++p) ss += red[p * 8 + t];
        float mk = amask[b * L2 + jh * 8 + t];
        cscale[t] = mk / (mk * ss + 1e-10f);
    }
    __syncthreads();
    float sc = cscale[jl];
    #pragma unroll
    for (int q = 0; q < 16; ++q) {
        int row = ii + q * 32;
        Xc[((size_t)b * XROWS + 1 + row) * XW + 320 + j] = __float2bfloat16(v[q] * sc);
    }
}

// ---------------- conv (round-7 schedule + T1 swizzle + 32x32x16 MFMA):
// same staging/barrier structure; fragments switched to mfma_f32_32x32x16_bf16
// (half the MFMA instructions for the same FLOPs; 2382 vs 2075 TF ceiling).
// Wave tile: M=64 (2x32) x N=64 (2x32), acc = f32x16[2][2] (64 AGPR, unchanged).
__global__ __launch_bounds__(256, 4) void conv_v7(
        const __hip_bfloat16* __restrict__ Xc,
        const __hip_bfloat16* __restrict__ Wp2,
        const __hip_bfloat16* __restrict__ Gt,
        const float* __restrict__ ctx_b,
        const float* __restrict__ gate_b,
        float* __restrict__ part) {
    __shared__ __align__(16) char lds[16 * EP_LD1 * 4];   // 16,640B; stage aliases front
    const int t = threadIdx.x, wave = t >> 6, lane = t & 63;
    const int lane31 = lane & 31, lh = lane >> 5;   // 32x32 operand decomposition
    const int flat = blockIdx.y * 16 + blockIdx.x;
    const int wf = (flat & 7) * 256 + (flat >> 3);  // m204 bijective XCD remap
    const int b = wf >> 4;
    const int wx = wf & 15;
    const int lb = wx >> 1, cb = wx & 1;
    const int l0 = lb * 64;
    const int role = wave ^ ((wx & 1) << 1);

    f32x16 acc[2][2];
    #pragma unroll
    for (int mt = 0; mt < 2; ++mt)
        #pragma unroll
        for (int nt = 0; nt < 2; ++nt) acc[mt][nt] = (f32x16)0.f;

    const char* XcB = (const char*)Xc + ((size_t)b * XROWS + l0) * ROW_B;
    const char* bbase = (const char*)Wp2 + (size_t)(cb * 4 + role) * WAVE_WP_B + lane * 16;

    #define STAGE_A(kc_, buf_) do {                                              \
        char* Ab_ = lds + (buf_) * ABUF_B;                                       \
        _Pragma("unroll")                                                        \
        for (int i = 0; i < 2; ++i) {                                            \
            int chunk = (i * 4 + wave) * 64 + lane;                              \
            if (chunk < 264) {                                                   \
                int row_ = chunk >> 2, c_ = chunk & 3;                           \
                int sc_ = (c_ ^ ((row_ >> 1) & 3)) << 4;                         \
                gload_lds16(XcB + (size_t)row_ * ROW_B + (kc_) * 64 + sc_,       \
                            Ab_ + (i * 4 + wave) * 1024);                        \
            }                                                                    \
        }                                                                        \
    } while (0)

    // A-frag for 32x32x16: row = mt*32 + lane31 + tap; k-quad qi = kh*2 + lh
    #define LOAD_AF(Ab_, mt_, kh_, tap_) (*(const bf16x8*)((Ab_) +               \
        (size_t)((mt_) * 32 + lane31 + (tap_)) * 64 +                            \
        ((((kh_) * 2 + lh) ^ ((((mt_) * 32 + lane31 + (tap_)) >> 1) & 3)) << 4)))

    STAGE_A(0, 0);
    __syncthreads();

    for (int kc = 0; kc < NKC; ++kc) {
        const int cbuf = kc & 1;
        if (kc < NKC - 1) STAGE_A(kc + 1, cbuf ^ 1);
        const char* Ab = lds + cbuf * ABUF_B;
        if (kc < 10) {
            #pragma unroll
            for (int tap = 0; tap < 3; ++tap) {
                bf16x8 bw[2][2];   // [nt][kh]
                #pragma unroll
                for (int nt = 0; nt < 2; ++nt)
                    #pragma unroll
                    for (int kh = 0; kh < 2; ++kh)
                        bw[nt][kh] = *(const bf16x8*)(bbase +
                            (size_t)((((kc * 3 + tap) * 2 + nt) * 2 + kh)) * 1024);
                bf16x8 af[2][2];   // [mt][kh]
                #pragma unroll
                for (int mt = 0; mt < 2; ++mt)
                    #pragma unroll
                    for (int kh = 0; kh < 2; ++kh)
                        af[mt][kh] = LOAD_AF(Ab, mt, kh, tap);
                #pragma unroll
                for (int mt = 0; mt < 2; ++mt)
                    #pragma unroll
                    for (int nt = 0; nt < 2; ++nt) {
                        acc[mt][nt] = __builtin_amdgcn_mfma_f32_32x32x16_bf16(
                            af[mt][0], bw[nt][0], acc[mt][nt], 0, 0, 0);
                        acc[mt][nt] = __builtin_amdgcn_mfma_f32_32x32x16_bf16(
                            af[mt][1], bw[nt][1], acc[mt][nt], 0, 0, 0);
                    }
            }
        } else if (role >= 2) {
            // kc==10: alpha (staged) x per-batch G-frags from Gt (L2)
            const char* GtB = (const char*)Gt + (size_t)b * 3 * (32 * 256 * 2);
            #pragma unroll
            for (int tap = 0; tap < 3; ++tap) {
                bf16x8 bw[2][2];
                #pragma unroll
                for (int nt = 0; nt < 2; ++nt)
                    #pragma unroll
                    for (int kh = 0; kh < 2; ++kh) {
                        #pragma unroll
                        for (int jj = 0; jj < 8; ++jj)
                            ((short*)&bw[nt][kh])[jj] = *(const short*)(GtB +
                                (size_t)tap * (32 * 256 * 2) +
                                (size_t)(kh * 16 + lh * 8 + jj) * 512 +
                                (size_t)(cb * 128 + (role & 1) * 64 + nt * 32 + lane31) * 2);
                    }
                bf16x8 af[2][2];
                #pragma unroll
                for (int mt = 0; mt < 2; ++mt)
                    #pragma unroll
                    for (int kh = 0; kh < 2; ++kh)
                        af[mt][kh] = LOAD_AF(Ab, mt, kh, tap);
                #pragma unroll
                for (int mt = 0; mt < 2; ++mt)
                    #pragma unroll
                    for (int nt = 0; nt < 2; ++nt) {
                        acc[mt][nt] = __builtin_amdgcn_mfma_f32_32x32x16_bf16(
                            af[mt][0], bw[nt][0], acc[mt][nt], 0, 0, 0);
                        acc[mt][nt] = __builtin_amdgcn_mfma_f32_32x32x16_bf16(
                            af[mt][1], bw[nt][1], acc[mt][nt], 0, 0, 0);
                    }
            }
        }
        __syncthreads();
    }
    #undef STAGE_A
    #undef LOAD_AF

    // epilogue: 4 slices of 16 rows; 32x32 C layout:
    // col = lane&31, row = (reg&3) + 8*(reg>>2) + 4*(lane>>5), reg in [0,16)
    const int c0 = cb * 128;
    const int cl = t & 127, rh = t >> 7;
    const float bs = ctx_b[c0 + cl];
    const float bg = gate_b[c0 + cl];
    float* ep = (float*)lds;
    float pm = -1e30f;
    for (int ms = 0; ms < 4; ++ms) {
        const int mt = ms >> 1, rHalf = ms & 1;
        __syncthreads();
        #pragma unroll
        for (int nt = 0; nt < 2; ++nt) {
            int col = (role << 6) + nt * 32 + lane31;
            #pragma unroll
            for (int rr = 0; rr < 8; ++rr) {
                int reg = rHalf * 8 + rr;
                int wrow = (rr & 3) + 8 * (rr >> 2) + 4 * lh;   // 0..15 within slice
                ep[wrow * EP_LD1 + col] = acc[mt][nt][reg];
            }
        }
        __syncthreads();
        #pragma unroll
        for (int rr = 0; rr < 8; ++rr) {
            int r = rh * 8 + rr;
            float sv = ep[r * EP_LD1 + cl] + bs;
            float gv = ep[r * EP_LD1 + 128 + cl] + bg;
            pm = fmaxf(pm, tanhf(sv) * fmaxf(gv, 0.f));
        }
    }
    __syncthreads();
    ep[t] = pm;
    __syncthreads();
    if (t < 128)
        part[((size_t)b * 8 + lb) * 256 + c0 + cl] = fmaxf(ep[t], ep[t + 128]);
}

// ---------------- final: max over 8 l-blocks + linear
__global__ __launch_bounds__(256) void finalize(const float* __restrict__ part,
                                                const float* __restrict__ lin_w,
                                                const float* __restrict__ lin_b,
                                                float* __restrict__ out) {
    __shared__ float pl[256];
    __shared__ float red[256];
    int b = blockIdx.x, t = threadIdx.x;
    float p = part[((size_t)b * 8) * 256 + t];
    for (int lb = 1; lb < 8; ++lb)
        p = fmaxf(p, part[((size_t)b * 8 + lb) * 256 + t]);
    pl[t] = p;
    __syncthreads();
    for (int n = 0; n < NCLASS; ++n) {
        red[t] = pl[t] * lin_w[n * NC + t];
        __syncthreads();
        for (int sft = 128; sft > 0; sft >>= 1) {
            if (t < sft) red[t] += red[t + sft];
            __syncthreads();
        }
        if (t == 0) out[b * NCLASS + n] = red[0] + lin_b[n];
        __syncthreads();
    }
}

extern "C" void kernel_launch(void* const* d_in, const int* in_sizes, int n_in,
                              void* d_out, int out_size, void* d_ws, size_t ws_size,
                              hipStream_t stream) {
    const int* cids = (const int*)d_in[0];
    const int* aids = (const int*)d_in[2];
    const float* amask = (const float*)d_in[3];
    const float* wordmat = (const float*)d_in[4];
    const float* Wm = (const float*)d_in[5];
    const float* ctx_w = (const float*)d_in[6];
    const float* ctx_b = (const float*)d_in[7];
    const float* gate_w = (const float*)d_in[8];
    const float* gate_b = (const float*)d_in[9];
    const float* lin_w = (const float*)d_in[10];
    const float* lin_b = (const float*)d_in[11];
    float* out = (float*)d_out;

    float* sbuf = (float*)d_ws;                                 // 2,097,152 f
    float* part = sbuf + 2097152;                               // 262,144 f
    __hip_bfloat16* aspb = (__hip_bfloat16*)(part + 262144);    // 1,310,720 bf16
    __hip_bfloat16* sybf = aspb + 1310720;                      // 1,310,720
    __hip_bfloat16* Wb   = sybf + 1310720;                      // 97,280
    __hip_bfloat16* Wp2  = Wb + WB_ELEMS;                       // 491,520
    __hip_bfloat16* Wg2  = Wp2 + WP2_ELEMS;                     // 245,760
    __hip_bfloat16* Gt   = Wg2 + WG2_ELEMS;                     // 3,145,728
    __hip_bfloat16* Xc   = Gt + GT_ELEMS;                       // 23,158,784

    prep_all<<<PREP_BLOCKS + XCAT_BLOCKS, 256, 0, stream>>>(
        ctx_w, gate_w, Wm, aids, cids, wordmat, Wp2, Wb, Wg2, aspb, sybf, Xc);
    asp_mfma<<<64 + BB * 3, 256, 0, stream>>>(aspb, Wb, Wg2, sybf, Gt);
    sxs_mfma<<<dim3(L1 / 64, BB), 256, 0, stream>>>(Xc, Wb, sybf, sbuf);
    softmax_col<<<dim3(BB, 4), 256, 0, stream>>>(sbuf, amask, Xc);
    conv_v7<<<dim3(16, BB), 256, 0, stream>>>(Xc, Wp2, Gt, ctx_b, gate_b, part);
    finalize<<<BB, 256, 0, stream>>>(part, lin_w, lin_b, out);
}

// Round 16
// 166.801 us; speedup vs baseline: 1.0569x; 1.0569x over previous
//
#include <hip/hip_runtime.h>
#include <hip/hip_bf16.h>
#include <math.h>
#include <stdint.h>

#define DIM 300
#define NC 256
#define KS 3
#define NCLASS 3
#define BB 128
#define L1 512
#define L2 32

#define XW 352            // Xc row: [emb 0..299 | 0 300..319 | alpha 320..351]
#define XROWS 514         // guard row + 512 + guard row, per batch
#define ROW_B (XW * 2)    // 704 bytes = 11 x 64B chunks
#define NKC 11            // conv K-chunks (kc 0..9 static, kc 10 = alpha x G)
#define WP2_ELEMS (2 * 4 * 10 * 3 * 4 * 64 * 8)   // 491,520 static conv B-frags
#define WB_ELEMS (10 * 19 * 64 * 8)               // 97,280: W for sx/sy
#define WG2_ELEMS (3 * 10 * 16 * 64 * 8)          // 245,760: w2 B-frags for G
#define GT_ELEMS (BB * 3 * 32 * 256)              // 3,145,728 plain G
#define GATH_ELEMS (BB * L2 * 320)                // 1,310,720 aspect gather
#define WAVE_WP_B (10 * 3 * 4 * 1024)             // 122,880 B per (cb,role)
#define PREP_BLOCKS ((WP2_ELEMS + WB_ELEMS + WG2_ELEMS + GATH_ELEMS) / 256)  // 8380
#define XCAT_BLOCKS (BB * L1 / 8)                 // 8192

#define ABUF_B 4224       // one A buffer (66 rows x 64B)
#define EP_LD1 260        // epilogue stride (floats), 256 cols + pad

typedef __attribute__((ext_vector_type(8))) short bf16x8;
typedef __attribute__((ext_vector_type(4))) short bf16x4;
typedef __attribute__((ext_vector_type(4))) float f32x4;

#define GLOBAL_AS __attribute__((address_space(1)))
#define LDS_AS __attribute__((address_space(3)))

__device__ __forceinline__ void gload_lds16(const void* g, void* l) {
    __builtin_amdgcn_global_load_lds((const GLOBAL_AS void*)g, (LDS_AS void*)l, 16, 0, 0);
}

static __device__ __forceinline__ short bfr(float x) {
    __hip_bfloat16 h = __float2bfloat16(x);
    return *(short*)&h;
}

// ---------------- one flat prep kernel: conv B-frags | W B-frags | w2 B-frags |
// aspect gather | (blocks >= PREP_BLOCKS) Xcat emb gather + guard rows
__global__ void prep_all(const float* __restrict__ ctx_w,
                         const float* __restrict__ gate_w,
                         const float* __restrict__ Wm,
                         const int* __restrict__ aids,
                         const int* __restrict__ cids,
                         const float* __restrict__ wordmat,
                         __hip_bfloat16* __restrict__ Wp2,
                         __hip_bfloat16* __restrict__ Wb,
                         __hip_bfloat16* __restrict__ Wg2,
                         __hip_bfloat16* __restrict__ aspb,
                         __hip_bfloat16* __restrict__ syb,
                         __hip_bfloat16* __restrict__ Xc) {
    if (blockIdx.x >= PREP_BLOCKS) {
        int xb = blockIdx.x - PREP_BLOCKS;
        int t = threadIdx.x;
        int rloc = t >> 5, lane = t & 31;
        int row = xb * 8 + rloc;                  // 0..65535
        int b = row >> 9, l = row & 511;
        size_t id = (size_t)cids[row];
        const float4* src = (const float4*)(wordmat + id * DIM);
        __hip_bfloat16* dst = Xc + ((size_t)b * XROWS + 1 + l) * XW;
        #pragma unroll
        for (int c = lane; c < 80; c += 32) {     // cols 0..319 (alpha written later)
            bf16x4 o;
            if (c < 75) {
                float4 f = src[c];
                o[0] = bfr(f.x); o[1] = bfr(f.y); o[2] = bfr(f.z); o[3] = bfr(f.w);
            } else {
                o = (bf16x4)0;   // cols 300..319
            }
            ((bf16x4*)dst)[c] = o;
        }
        if (xb < 256 && t < 88) {                 // zero guard rows
            int b2 = xb >> 1;
            int gr = (xb & 1) ? (XROWS - 1) : 0;
            ((bf16x4*)(Xc + ((size_t)b2 * XROWS + gr) * XW))[t] = (bf16x4)0;
        }
        return;
    }
    int idx = blockIdx.x * 256 + threadIdx.x;
    if (idx < WP2_ELEMS) {
        int jj = idx & 7;
        int lane = (idx >> 3) & 63;
        int n = (idx >> 9) & 3;
        int rest = idx >> 11;
        int tap = rest % 3;
        int r2 = rest / 3;
        int kc = r2 % 10;
        int w = r2 / 10;
        int role = w & 3, cbv = w >> 2;
        int k = kc * 32 + ((lane >> 4) << 3) + jj;
        int nl = role * 64 + n * 16 + (lane & 15);
        float v = 0.f;
        if (nl < 128) {
            int ch = cbv * 128 + nl;
            if (k < 300) v = ctx_w[(ch * DIM + k) * KS + tap];
        } else {
            int ch = cbv * 128 + (nl - 128);
            if (k < 300) v = gate_w[(ch * 2 * DIM + k) * KS + tap];
        }
        Wp2[idx] = __float2bfloat16(v);
        return;
    }
    idx -= WP2_ELEMS;
    if (idx < WB_ELEMS) {
        int j = idx & 7;
        int l = (idx >> 3) & 63;
        int r = idx >> 9;
        int nf = r % 19, kc = r / 19;
        int k = kc * 32 + ((l >> 4) << 3) + j;
        int n = nf * 16 + (l & 15);
        float v = (k < 300 && n < 300) ? Wm[k * DIM + n] : 0.f;
        Wb[idx] = __float2bfloat16(v);
        return;
    }
    idx -= WB_ELEMS;
    if (idx < WG2_ELEMS) {
        int jj = idx & 7;
        int lane = (idx >> 3) & 63;
        int rest = idx >> 9;
        int nf = rest % 16;
        int r2 = rest / 16;
        int kc = r2 % 10, tap = r2 / 10;
        int k = kc * 32 + ((lane >> 4) << 3) + jj;
        int n = nf * 16 + (lane & 15);
        float v = (k < 300) ? gate_w[(n * 2 * DIM + DIM + k) * KS + tap] : 0.f;
        Wg2[idx] = __float2bfloat16(v);
        return;
    }
    idx -= WG2_ELEMS;
    if (idx < GATH_ELEMS) {
        int row = idx / 320, d = idx - row * 320;
        if (d < DIM) {
            aspb[(size_t)row * 320 + d] = __float2bfloat16(wordmat[(size_t)aids[row] * DIM + d]);
        } else {
            aspb[(size_t)row * 320 + d] = __float2bfloat16(0.f);
            if (d >= 304) syb[(size_t)row * 320 + d] = __float2bfloat16(0.f);
        }
    }
}

// ---------------- merged aspect MFMA: sy = relu(aspect@W) [blocks 0..63]
//                  and G[b,tap] = aspect[b] @ w2^T [blocks 64..447]
__global__ __launch_bounds__(256, 2) void asp_mfma(
        const __hip_bfloat16* __restrict__ aspb,
        const __hip_bfloat16* __restrict__ Wb,
        const __hip_bfloat16* __restrict__ Wg2,
        __hip_bfloat16* __restrict__ syb,
        __hip_bfloat16* __restrict__ Gt) {
    const int t = threadIdx.x, wave = t >> 6, l = t & 63;
    const int lane15 = l & 15, lq = l >> 4;
    if (blockIdx.x < 64) {
        const int g = blockIdx.x * 64 + wave * 16 + lane15;
        f32x4 acc[19];
        #pragma unroll
        for (int nf = 0; nf < 19; ++nf) acc[nf] = (f32x4)0.f;
        const bf16x8* Arow = (const bf16x8*)((const char*)aspb + (size_t)g * 640);
        const bf16x8* WbV = (const bf16x8*)Wb;
        for (int kc = 0; kc < 10; ++kc) {
            bf16x8 af = Arow[kc * 4 + lq];
            #pragma unroll
            for (int nf = 0; nf < 19; ++nf)
                acc[nf] = __builtin_amdgcn_mfma_f32_16x16x32_bf16(
                    af, WbV[(kc * 19 + nf) * 64 + l], acc[nf], 0, 0, 0);
        }
        #pragma unroll
        for (int nf = 0; nf < 19; ++nf) {
            int col = nf * 16 + lane15;
            #pragma unroll
            for (int i2 = 0; i2 < 4; ++i2) {
                int row = blockIdx.x * 64 + wave * 16 + lq * 4 + i2;
                syb[(size_t)row * 320 + col] = __float2bfloat16(fmaxf(acc[nf][i2], 0.f));
            }
        }
    } else {
        const int i = blockIdx.x - 64;
        const int b = i / 3, tap = i - b * 3;
        f32x4 acc[2][4];
        #pragma unroll
        for (int m = 0; m < 2; ++m)
            #pragma unroll
            for (int ni = 0; ni < 4; ++ni) acc[m][ni] = (f32x4)0.f;
        const char* Ab = (const char*)aspb + (size_t)b * 32 * 640;
        const bf16x8* WgV = (const bf16x8*)Wg2;
        for (int kc = 0; kc < 10; ++kc) {
            bf16x8 af[2];
            #pragma unroll
            for (int m = 0; m < 2; ++m)
                af[m] = *(const bf16x8*)(Ab + (size_t)(m * 16 + lane15) * 640 + kc * 64 + lq * 16);
            #pragma unroll
            for (int ni = 0; ni < 4; ++ni) {
                bf16x8 bw = WgV[((size_t)(tap * 10 + kc) * 16 + wave * 4 + ni) * 64 + l];
                #pragma unroll
                for (int m = 0; m < 2; ++m)
                    acc[m][ni] = __builtin_amdgcn_mfma_f32_16x16x32_bf16(af[m], bw, acc[m][ni], 0, 0, 0);
            }
        }
        #pragma unroll
        for (int m = 0; m < 2; ++m)
            #pragma unroll
            for (int ni = 0; ni < 4; ++ni) {
                int c = (wave * 4 + ni) * 16 + lane15;
                #pragma unroll
                for (int i2 = 0; i2 < 4; ++i2) {
                    int j = m * 16 + lq * 4 + i2;
                    Gt[((size_t)(b * 3 + tap) * 32 + j) * 256 + c] = __float2bfloat16(acc[m][ni][i2]);
                }
            }
    }
}

// ---------------- fused sx+s: 64 rows/block, T1 bijective XCD swizzle
__global__ __launch_bounds__(256, 2) void sxs_mfma(
        const __hip_bfloat16* __restrict__ Xc,
        const __hip_bfloat16* __restrict__ Wb,
        const __hip_bfloat16* __restrict__ syb,
        float* __restrict__ s) {
    __shared__ __align__(16) char sxL[4 * 16 * 640];  // 40KB, wave-private
    const int t = threadIdx.x, wave = t >> 6, l = t & 63;
    const int lane15 = l & 15, lq = l >> 4;
    const int flat = blockIdx.y * 8 + blockIdx.x;
    const int wf = (flat & 7) * 128 + (flat >> 3);
    const int lb = wf & 7, b = wf >> 3;
    const int g = b * XROWS + 1 + lb * 64 + wave * 16 + lane15;

    f32x4 acc[19];
    #pragma unroll
    for (int nf = 0; nf < 19; ++nf) acc[nf] = (f32x4)0.f;

    const bf16x8* Arow = (const bf16x8*)((const char*)Xc + (size_t)g * ROW_B);
    const bf16x8* WbV = (const bf16x8*)Wb;
    for (int kc = 0; kc < 10; ++kc) {
        bf16x8 af = Arow[kc * 4 + lq];
        #pragma unroll
        for (int nf = 0; nf < 19; ++nf)
            acc[nf] = __builtin_amdgcn_mfma_f32_16x16x32_bf16(
                af, WbV[(kc * 19 + nf) * 64 + l], acc[nf], 0, 0, 0);
    }

    char* sxW = sxL + wave * (16 * 640);
    if (l < 32) {
        int row = l >> 1;
        int phys = (2 + (l & 1)) ^ ((row >> 2) & 3);
        *(f32x4*)(sxW + row * 640 + 576 + phys * 16) = (f32x4)0.f;
    }
    #pragma unroll
    for (int nf = 0; nf < 19; ++nf) {
        int col = nf * 16 + lane15;
        #pragma unroll
        for (int i2 = 0; i2 < 4; ++i2) {
            int row = lq * 4 + i2;
            int off = row * 640 + ((col >> 5) << 6) +
                      ((((col >> 3) & 3) ^ ((row >> 2) & 3)) << 4) + ((col & 7) << 1);
            *(__hip_bfloat16*)(sxW + off) = __float2bfloat16(fmaxf(acc[nf][i2], 0.f));
        }
    }
    f32x4 acc2[2];
    acc2[0] = (f32x4)0.f;
    acc2[1] = (f32x4)0.f;
    const bf16x8* syV = (const bf16x8*)syb + (size_t)b * 32 * 40;
    for (int kc = 0; kc < 10; ++kc) {
        bf16x8 af2 = *(const bf16x8*)(sxW + lane15 * 640 + kc * 64 +
                                      ((lq ^ ((lane15 >> 2) & 3)) << 4));
        #pragma unroll
        for (int nj = 0; nj < 2; ++nj) {
            bf16x8 bfj = syV[(nj * 16 + lane15) * 40 + kc * 4 + lq];
            acc2[nj] = __builtin_amdgcn_mfma_f32_16x16x32_bf16(af2, bfj, acc2[nj], 0, 0, 0);
        }
    }
    #pragma unroll
    for (int nj = 0; nj < 2; ++nj)
        #pragma unroll
        for (int i2 = 0; i2 < 4; ++i2) {
            int i = lb * 64 + wave * 16 + lq * 4 + i2;
            s[((size_t)b * L1 + i) * L2 + nj * 16 + lane15] = acc2[nj][i2];
        }
}

// ---------------- softmax over dim=1 (L1): bf16 alpha straight into Xc[320..351]
__global__ __launch_bounds__(256) void softmax_col(const float* __restrict__ s,
                                                   const float* __restrict__ amask,
                                                   __hip_bfloat16* __restrict__ Xc) {
    __shared__ float red[256];
    __shared__ float cmax[8], cscale[8];
    int b = blockIdx.x, jh = blockIdx.y, t = threadIdx.x;
    int jl = t & 7, j = jh * 8 + jl, ii = t >> 3;
    const float* sb = s + (size_t)b * L1 * L2;
    float v[16];
    float m = -1e30f;
    #pragma unroll
    for (int q = 0; q < 16; ++q) {
        v[q] = sb[(size_t)(ii + q * 32) * L2 + j];
        m = fmaxf(m, v[q]);
    }
    red[t] = m;
    __syncthreads();
    if (t < 8) {
        float mm = red[t];
        for (int p = 1; p < 32; ++p) mm = fmaxf(mm, red[p * 8 + t]);
        cmax[t] = mm;
    }
    __syncthreads();
    float cm = cmax[jl];
    float sum = 0.f;
    #pragma unroll
    for (int q = 0; q < 16; ++q) {
        v[q] = expf(v[q] - cm);
        sum += v[q];
    }
    red[t] = sum;
    __syncthreads();
    if (t < 8) {
        float ss = 0.f;
        for (int p = 0; p < 32; ++p) ss += red[p * 8 + t];
        float mk = amask[b * L2 + jh * 8 + t];
        cscale[t] = mk / (mk * ss + 1e-10f);
    }
    __syncthreads();
    float sc = cscale[jl];
    #pragma unroll
    for (int q = 0; q < 16; ++q) {
        int row = ii + q * 32;
        Xc[((size_t)b * XROWS + 1 + row) * XW + 320 + j] = __float2bfloat16(v[q] * sc);
    }
}

// ---------------- conv (proven R14: round-7 schedule + T1 XCD swizzle, 16x16):
// 256-thr, cb-split blocks, per-kc A double-buffer via global_load_lds,
// B direct-global, role-XOR balance. [R15 lesson: 32x32 frags reintroduce 4-way
// LDS conflicts on the 64B-row A layout (row r / r+2 bank-alias) — reverted.]
__global__ __launch_bounds__(256, 4) void conv_v7(
        const __hip_bfloat16* __restrict__ Xc,
        const __hip_bfloat16* __restrict__ Wp2,
        const __hip_bfloat16* __restrict__ Gt,
        const float* __restrict__ ctx_b,
        const float* __restrict__ gate_b,
        float* __restrict__ part) {
    __shared__ __align__(16) char lds[16 * EP_LD1 * 4];   // 16,640B; stage aliases front
    const int t = threadIdx.x, wave = t >> 6, lane = t & 63;
    const int lane15 = lane & 15, lq = lane >> 4;
    // nwg = 2048 = 8 * 256; wf = (flat%8)*256 + flat/8 (m204 bijective remap)
    const int flat = blockIdx.y * 16 + blockIdx.x;
    const int wf = (flat & 7) * 256 + (flat >> 3);
    const int b = wf >> 4;
    const int wx = wf & 15;
    const int lb = wx >> 1, cb = wx & 1;
    const int l0 = lb * 64;
    const int role = wave ^ ((wx & 1) << 1);

    f32x4 acc[4][4];
    #pragma unroll
    for (int m = 0; m < 4; ++m)
        #pragma unroll
        for (int n = 0; n < 4; ++n) acc[m][n] = (f32x4)0.f;

    const char* XcB = (const char*)Xc + ((size_t)b * XROWS + l0) * ROW_B;
    const char* bbase = (const char*)Wp2 + (size_t)(cb * 4 + role) * WAVE_WP_B + lane * 16;

    #define STAGE_A(kc_, buf_) do {                                              \
        char* Ab_ = lds + (buf_) * ABUF_B;                                       \
        _Pragma("unroll")                                                        \
        for (int i = 0; i < 2; ++i) {                                            \
            int chunk = (i * 4 + wave) * 64 + lane;                              \
            if (chunk < 264) {                                                   \
                int row_ = chunk >> 2, c_ = chunk & 3;                           \
                int sc_ = (c_ ^ ((row_ >> 1) & 3)) << 4;                         \
                gload_lds16(XcB + (size_t)row_ * ROW_B + (kc_) * 64 + sc_,       \
                            Ab_ + (i * 4 + wave) * 1024);                        \
            }                                                                    \
        }                                                                        \
    } while (0)

    STAGE_A(0, 0);
    __syncthreads();

    for (int kc = 0; kc < NKC; ++kc) {
        const int cbuf = kc & 1;
        if (kc < NKC - 1) STAGE_A(kc + 1, cbuf ^ 1);
        const char* Ab = lds + cbuf * ABUF_B;
        if (kc < 10) {
            #pragma unroll
            for (int tap = 0; tap < 3; ++tap) {
                bf16x8 bw[4];
                #pragma unroll
                for (int n = 0; n < 4; ++n)
                    bw[n] = *(const bf16x8*)(bbase + (size_t)((kc * 3 + tap) * 4 + n) * 1024);
                bf16x8 af[4];
                #pragma unroll
                for (int m = 0; m < 4; ++m) {
                    int row = m * 16 + lane15 + tap;
                    af[m] = *(const bf16x8*)(Ab + row * 64 + ((lq ^ ((row >> 1) & 3)) << 4));
                }
                #pragma unroll
                for (int m = 0; m < 4; ++m)
                    #pragma unroll
                    for (int n = 0; n < 4; ++n)
                        acc[m][n] = __builtin_amdgcn_mfma_f32_16x16x32_bf16(
                            af[m], bw[n], acc[m][n], 0, 0, 0);
            }
        } else if (role >= 2) {
            const char* GtB = (const char*)Gt + (size_t)b * 3 * (32 * 256 * 2);
            #pragma unroll
            for (int tap = 0; tap < 3; ++tap) {
                bf16x8 bw[4];
                #pragma unroll
                for (int n = 0; n < 4; ++n) {
                    #pragma unroll
                    for (int jj = 0; jj < 8; ++jj)
                        ((short*)&bw[n])[jj] = *(const short*)(GtB +
                            (size_t)tap * (32 * 256 * 2) +
                            (size_t)(lq * 8 + jj) * 512 +
                            (size_t)(cb * 128 + (role & 1) * 64 + n * 16 + lane15) * 2);
                }
                bf16x8 af[4];
                #pragma unroll
                for (int m = 0; m < 4; ++m) {
                    int row = m * 16 + lane15 + tap;
                    af[m] = *(const bf16x8*)(Ab + row * 64 + ((lq ^ ((row >> 1) & 3)) << 4));
                }
                #pragma unroll
                for (int m = 0; m < 4; ++m)
                    #pragma unroll
                    for (int n = 0; n < 4; ++n)
                        acc[m][n] = __builtin_amdgcn_mfma_f32_16x16x32_bf16(
                            af[m], bw[n], acc[m][n], 0, 0, 0);
            }
        }
        __syncthreads();
    }
    #undef STAGE_A

    const int c0 = cb * 128;
    const int cl = t & 127, rh = t >> 7;
    const float bs = ctx_b[c0 + cl];
    const float bg = gate_b[c0 + cl];
    float* ep = (float*)lds;
    float pm = -1e30f;
    for (int ms = 0; ms < 4; ++ms) {
        __syncthreads();
        #pragma unroll
        for (int n = 0; n < 4; ++n) {
            int col = (role << 6) + (n << 4) + lane15;
            #pragma unroll
            for (int i2 = 0; i2 < 4; ++i2)
                ep[(lq * 4 + i2) * EP_LD1 + col] = acc[ms][n][i2];
        }
        __syncthreads();
        #pragma unroll
        for (int rr = 0; rr < 8; ++rr) {
            int r = rh * 8 + rr;
            float sv = ep[r * EP_LD1 + cl] + bs;
            float gv = ep[r * EP_LD1 + 128 + cl] + bg;
            pm = fmaxf(pm, tanhf(sv) * fmaxf(gv, 0.f));
        }
    }
    __syncthreads();
    ep[t] = pm;
    __syncthreads();
    if (t < 128)
        part[((size_t)b * 8 + lb) * 256 + c0 + cl] = fmaxf(ep[t], ep[t + 128]);
}

// ---------------- final: max over 8 l-blocks + linear
__global__ __launch_bounds__(256) void finalize(const float* __restrict__ part,
                                                const float* __restrict__ lin_w,
                                                const float* __restrict__ lin_b,
                                                float* __restrict__ out) {
    __shared__ float pl[256];
    __shared__ float red[256];
    int b = blockIdx.x, t = threadIdx.x;
    float p = part[((size_t)b * 8) * 256 + t];
    for (int lb = 1; lb < 8; ++lb)
        p = fmaxf(p, part[((size_t)b * 8 + lb) * 256 + t]);
    pl[t] = p;
    __syncthreads();
    for (int n = 0; n < NCLASS; ++n) {
        red[t] = pl[t] * lin_w[n * NC + t];
        __syncthreads();
        for (int sft = 128; sft > 0; sft >>= 1) {
            if (t < sft) red[t] += red[t + sft];
            __syncthreads();
        }
        if (t == 0) out[b * NCLASS + n] = red[0] + lin_b[n];
        __syncthreads();
    }
}

extern "C" void kernel_launch(void* const* d_in, const int* in_sizes, int n_in,
                              void* d_out, int out_size, void* d_ws, size_t ws_size,
                              hipStream_t stream) {
    const int* cids = (const int*)d_in[0];
    const int* aids = (const int*)d_in[2];
    const float* amask = (const float*)d_in[3];
    const float* wordmat = (const float*)d_in[4];
    const float* Wm = (const float*)d_in[5];
    const float* ctx_w = (const float*)d_in[6];
    const float* ctx_b = (const float*)d_in[7];
    const float* gate_w = (const float*)d_in[8];
    const float* gate_b = (const float*)d_in[9];
    const float* lin_w = (const float*)d_in[10];
    const float* lin_b = (const float*)d_in[11];
    float* out = (float*)d_out;

    float* sbuf = (float*)d_ws;                                 // 2,097,152 f
    float* part = sbuf + 2097152;                               // 262,144 f
    __hip_bfloat16* aspb = (__hip_bfloat16*)(part + 262144);    // 1,310,720 bf16
    __hip_bfloat16* sybf = aspb + 1310720;                      // 1,310,720
    __hip_bfloat16* Wb   = sybf + 1310720;                      // 97,280
    __hip_bfloat16* Wp2  = Wb + WB_ELEMS;                       // 491,520
    __hip_bfloat16* Wg2  = Wp2 + WP2_ELEMS;                     // 245,760
    __hip_bfloat16* Gt   = Wg2 + WG2_ELEMS;                     // 3,145,728
    __hip_bfloat16* Xc   = Gt + GT_ELEMS;                       // 23,158,784

    prep_all<<<PREP_BLOCKS + XCAT_BLOCKS, 256, 0, stream>>>(
        ctx_w, gate_w, Wm, aids, cids, wordmat, Wp2, Wb, Wg2, aspb, sybf, Xc);
    asp_mfma<<<64 + BB * 3, 256, 0, stream>>>(aspb, Wb, Wg2, sybf, Gt);
    sxs_mfma<<<dim3(L1 / 64, BB), 256, 0, stream>>>(Xc, Wb, sybf, sbuf);
    softmax_col<<<dim3(BB, 4), 256, 0, stream>>>(sbuf, amask, Xc);
    conv_v7<<<dim3(16, BB), 256, 0, stream>>>(Xc, Wp2, Gt, ctx_b, gate_b, part);
    finalize<<<BB, 256, 0, stream>>>(part, lin_w, lin_b, out);
}

// Round 17
// 165.412 us; speedup vs baseline: 1.0658x; 1.0084x over previous
//
#include <hip/hip_runtime.h>
#include <hip/hip_bf16.h>
#include <math.h>
#include <stdint.h>

#define DIM 300
#define NC 256
#define KS 3
#define NCLASS 3
#define BB 128
#define L1 512
#define L2 32

#define XW 352            // Xc row: [emb 0..299 | 0 300..319 | alpha 320..351]
#define XROWS 514         // guard row + 512 + guard row, per batch
#define ROW_B (XW * 2)    // 704 bytes = 11 x 64B chunks
#define NKC 11            // conv K-chunks (kc 0..9 static, kc 10 = alpha x G)
#define WP2_ELEMS (2 * 4 * 10 * 3 * 4 * 64 * 8)   // 491,520 static conv B-frags
#define WB_ELEMS (10 * 19 * 64 * 8)               // 97,280: W for sx/sy
#define WG2_ELEMS (3 * 10 * 16 * 64 * 8)          // 245,760: w2 B-frags for G
#define GT_ELEMS (BB * 3 * 32 * 256)              // 3,145,728 plain G
#define GATH_ELEMS (BB * L2 * 320)                // 1,310,720 aspect gather
#define WAVE_WP_B (10 * 3 * 4 * 1024)             // 122,880 B per (cb,role)
#define PREP_BLOCKS ((WP2_ELEMS + WB_ELEMS + WG2_ELEMS + GATH_ELEMS) / 256)  // 8380
#define XCAT_BLOCKS (BB * L1 / 8)                 // 8192

#define ABUF_B 4224       // one A buffer (66 rows x 64B)
#define EP_LD1 260        // epilogue stride (floats), 256 cols + pad

typedef __attribute__((ext_vector_type(8))) short bf16x8;
typedef __attribute__((ext_vector_type(4))) short bf16x4;
typedef __attribute__((ext_vector_type(4))) float f32x4;

#define GLOBAL_AS __attribute__((address_space(1)))
#define LDS_AS __attribute__((address_space(3)))

__device__ __forceinline__ void gload_lds16(const void* g, void* l) {
    __builtin_amdgcn_global_load_lds((const GLOBAL_AS void*)g, (LDS_AS void*)l, 16, 0, 0);
}

static __device__ __forceinline__ short bfr(float x) {
    __hip_bfloat16 h = __float2bfloat16(x);
    return *(short*)&h;
}

// ---------------- one flat prep kernel: conv B-frags | W B-frags | w2 B-frags |
// aspect gather | (blocks >= PREP_BLOCKS) Xcat emb gather + guard rows
__global__ void prep_all(const float* __restrict__ ctx_w,
                         const float* __restrict__ gate_w,
                         const float* __restrict__ Wm,
                         const int* __restrict__ aids,
                         const int* __restrict__ cids,
                         const float* __restrict__ wordmat,
                         __hip_bfloat16* __restrict__ Wp2,
                         __hip_bfloat16* __restrict__ Wb,
                         __hip_bfloat16* __restrict__ Wg2,
                         __hip_bfloat16* __restrict__ aspb,
                         __hip_bfloat16* __restrict__ syb,
                         __hip_bfloat16* __restrict__ Xc) {
    if (blockIdx.x >= PREP_BLOCKS) {
        int xb = blockIdx.x - PREP_BLOCKS;
        int t = threadIdx.x;
        int rloc = t >> 5, lane = t & 31;
        int row = xb * 8 + rloc;                  // 0..65535
        int b = row >> 9, l = row & 511;
        size_t id = (size_t)cids[row];
        const float4* src = (const float4*)(wordmat + id * DIM);
        __hip_bfloat16* dst = Xc + ((size_t)b * XROWS + 1 + l) * XW;
        #pragma unroll
        for (int c = lane; c < 80; c += 32) {     // cols 0..319 (alpha written later)
            bf16x4 o;
            if (c < 75) {
                float4 f = src[c];
                o[0] = bfr(f.x); o[1] = bfr(f.y); o[2] = bfr(f.z); o[3] = bfr(f.w);
            } else {
                o = (bf16x4)0;   // cols 300..319
            }
            ((bf16x4*)dst)[c] = o;
        }
        if (xb < 256 && t < 88) {                 // zero guard rows
            int b2 = xb >> 1;
            int gr = (xb & 1) ? (XROWS - 1) : 0;
            ((bf16x4*)(Xc + ((size_t)b2 * XROWS + gr) * XW))[t] = (bf16x4)0;
        }
        return;
    }
    int idx = blockIdx.x * 256 + threadIdx.x;
    if (idx < WP2_ELEMS) {
        int jj = idx & 7;
        int lane = (idx >> 3) & 63;
        int n = (idx >> 9) & 3;
        int rest = idx >> 11;
        int tap = rest % 3;
        int r2 = rest / 3;
        int kc = r2 % 10;
        int w = r2 / 10;
        int role = w & 3, cbv = w >> 2;
        int k = kc * 32 + ((lane >> 4) << 3) + jj;
        int nl = role * 64 + n * 16 + (lane & 15);
        float v = 0.f;
        if (nl < 128) {
            int ch = cbv * 128 + nl;
            if (k < 300) v = ctx_w[(ch * DIM + k) * KS + tap];
        } else {
            int ch = cbv * 128 + (nl - 128);
            if (k < 300) v = gate_w[(ch * 2 * DIM + k) * KS + tap];
        }
        Wp2[idx] = __float2bfloat16(v);
        return;
    }
    idx -= WP2_ELEMS;
    if (idx < WB_ELEMS) {
        int j = idx & 7;
        int l = (idx >> 3) & 63;
        int r = idx >> 9;
        int nf = r % 19, kc = r / 19;
        int k = kc * 32 + ((l >> 4) << 3) + j;
        int n = nf * 16 + (l & 15);
        float v = (k < 300 && n < 300) ? Wm[k * DIM + n] : 0.f;
        Wb[idx] = __float2bfloat16(v);
        return;
    }
    idx -= WB_ELEMS;
    if (idx < WG2_ELEMS) {
        int jj = idx & 7;
        int lane = (idx >> 3) & 63;
        int rest = idx >> 9;
        int nf = rest % 16;
        int r2 = rest / 16;
        int kc = r2 % 10, tap = r2 / 10;
        int k = kc * 32 + ((lane >> 4) << 3) + jj;
        int n = nf * 16 + (lane & 15);
        float v = (k < 300) ? gate_w[(n * 2 * DIM + DIM + k) * KS + tap] : 0.f;
        Wg2[idx] = __float2bfloat16(v);
        return;
    }
    idx -= WG2_ELEMS;
    if (idx < GATH_ELEMS) {
        int row = idx / 320, d = idx - row * 320;
        if (d < DIM) {
            aspb[(size_t)row * 320 + d] = __float2bfloat16(wordmat[(size_t)aids[row] * DIM + d]);
        } else {
            aspb[(size_t)row * 320 + d] = __float2bfloat16(0.f);
            if (d >= 304) syb[(size_t)row * 320 + d] = __float2bfloat16(0.f);
        }
    }
}

// ---------------- merged aspect MFMA: sy = relu(aspect@W) [blocks 0..63]
//                  and G[b,tap] = aspect[b] @ w2^T [blocks 64..447]
__global__ __launch_bounds__(256, 2) void asp_mfma(
        const __hip_bfloat16* __restrict__ aspb,
        const __hip_bfloat16* __restrict__ Wb,
        const __hip_bfloat16* __restrict__ Wg2,
        __hip_bfloat16* __restrict__ syb,
        __hip_bfloat16* __restrict__ Gt) {
    const int t = threadIdx.x, wave = t >> 6, l = t & 63;
    const int lane15 = l & 15, lq = l >> 4;
    if (blockIdx.x < 64) {
        const int g = blockIdx.x * 64 + wave * 16 + lane15;
        f32x4 acc[19];
        #pragma unroll
        for (int nf = 0; nf < 19; ++nf) acc[nf] = (f32x4)0.f;
        const bf16x8* Arow = (const bf16x8*)((const char*)aspb + (size_t)g * 640);
        const bf16x8* WbV = (const bf16x8*)Wb;
        #pragma unroll 2
        for (int kc = 0; kc < 10; ++kc) {
            bf16x8 af = Arow[kc * 4 + lq];
            #pragma unroll
            for (int nf = 0; nf < 19; ++nf)
                acc[nf] = __builtin_amdgcn_mfma_f32_16x16x32_bf16(
                    af, WbV[(kc * 19 + nf) * 64 + l], acc[nf], 0, 0, 0);
        }
        #pragma unroll
        for (int nf = 0; nf < 19; ++nf) {
            int col = nf * 16 + lane15;
            #pragma unroll
            for (int i2 = 0; i2 < 4; ++i2) {
                int row = blockIdx.x * 64 + wave * 16 + lq * 4 + i2;
                syb[(size_t)row * 320 + col] = __float2bfloat16(fmaxf(acc[nf][i2], 0.f));
            }
        }
    } else {
        const int i = blockIdx.x - 64;
        const int b = i / 3, tap = i - b * 3;
        f32x4 acc[2][4];
        #pragma unroll
        for (int m = 0; m < 2; ++m)
            #pragma unroll
            for (int ni = 0; ni < 4; ++ni) acc[m][ni] = (f32x4)0.f;
        const char* Ab = (const char*)aspb + (size_t)b * 32 * 640;
        const bf16x8* WgV = (const bf16x8*)Wg2;
        #pragma unroll 2
        for (int kc = 0; kc < 10; ++kc) {
            bf16x8 af[2];
            #pragma unroll
            for (int m = 0; m < 2; ++m)
                af[m] = *(const bf16x8*)(Ab + (size_t)(m * 16 + lane15) * 640 + kc * 64 + lq * 16);
            #pragma unroll
            for (int ni = 0; ni < 4; ++ni) {
                bf16x8 bw = WgV[((size_t)(tap * 10 + kc) * 16 + wave * 4 + ni) * 64 + l];
                #pragma unroll
                for (int m = 0; m < 2; ++m)
                    acc[m][ni] = __builtin_amdgcn_mfma_f32_16x16x32_bf16(af[m], bw, acc[m][ni], 0, 0, 0);
            }
        }
        #pragma unroll
        for (int m = 0; m < 2; ++m)
            #pragma unroll
            for (int ni = 0; ni < 4; ++ni) {
                int c = (wave * 4 + ni) * 16 + lane15;
                #pragma unroll
                for (int i2 = 0; i2 < 4; ++i2) {
                    int j = m * 16 + lq * 4 + i2;
                    Gt[((size_t)(b * 3 + tap) * 32 + j) * 256 + c] = __float2bfloat16(acc[m][ni][i2]);
                }
            }
    }
}

// ---------------- fused sx+s: 64 rows/block, T1 bijective XCD swizzle.
// R17: kc loops unrolled (x2 phase1, full phase2) — at 2 blocks/CU latency
// hiding must come from ILP; unrolling keeps B-loads of adjacent kc in flight.
__global__ __launch_bounds__(256, 2) void sxs_mfma(
        const __hip_bfloat16* __restrict__ Xc,
        const __hip_bfloat16* __restrict__ Wb,
        const __hip_bfloat16* __restrict__ syb,
        float* __restrict__ s) {
    __shared__ __align__(16) char sxL[4 * 16 * 640];  // 40KB, wave-private
    const int t = threadIdx.x, wave = t >> 6, l = t & 63;
    const int lane15 = l & 15, lq = l >> 4;
    const int flat = blockIdx.y * 8 + blockIdx.x;
    const int wf = (flat & 7) * 128 + (flat >> 3);
    const int lb = wf & 7, b = wf >> 3;
    const int g = b * XROWS + 1 + lb * 64 + wave * 16 + lane15;

    f32x4 acc[19];
    #pragma unroll
    for (int nf = 0; nf < 19; ++nf) acc[nf] = (f32x4)0.f;

    const bf16x8* Arow = (const bf16x8*)((const char*)Xc + (size_t)g * ROW_B);
    const bf16x8* WbV = (const bf16x8*)Wb;
    #pragma unroll 2
    for (int kc = 0; kc < 10; ++kc) {
        bf16x8 af = Arow[kc * 4 + lq];
        #pragma unroll
        for (int nf = 0; nf < 19; ++nf)
            acc[nf] = __builtin_amdgcn_mfma_f32_16x16x32_bf16(
                af, WbV[(kc * 19 + nf) * 64 + l], acc[nf], 0, 0, 0);
    }

    char* sxW = sxL + wave * (16 * 640);
    if (l < 32) {
        int row = l >> 1;
        int phys = (2 + (l & 1)) ^ ((row >> 2) & 3);
        *(f32x4*)(sxW + row * 640 + 576 + phys * 16) = (f32x4)0.f;
    }
    #pragma unroll
    for (int nf = 0; nf < 19; ++nf) {
        int col = nf * 16 + lane15;
        #pragma unroll
        for (int i2 = 0; i2 < 4; ++i2) {
            int row = lq * 4 + i2;
            int off = row * 640 + ((col >> 5) << 6) +
                      ((((col >> 3) & 3) ^ ((row >> 2) & 3)) << 4) + ((col & 7) << 1);
            *(__hip_bfloat16*)(sxW + off) = __float2bfloat16(fmaxf(acc[nf][i2], 0.f));
        }
    }
    f32x4 acc2[2];
    acc2[0] = (f32x4)0.f;
    acc2[1] = (f32x4)0.f;
    const bf16x8* syV = (const bf16x8*)syb + (size_t)b * 32 * 40;
    #pragma unroll
    for (int kc = 0; kc < 10; ++kc) {
        bf16x8 af2 = *(const bf16x8*)(sxW + lane15 * 640 + kc * 64 +
                                      ((lq ^ ((lane15 >> 2) & 3)) << 4));
        #pragma unroll
        for (int nj = 0; nj < 2; ++nj) {
            bf16x8 bfj = syV[(nj * 16 + lane15) * 40 + kc * 4 + lq];
            acc2[nj] = __builtin_amdgcn_mfma_f32_16x16x32_bf16(af2, bfj, acc2[nj], 0, 0, 0);
        }
    }
    #pragma unroll
    for (int nj = 0; nj < 2; ++nj)
        #pragma unroll
        for (int i2 = 0; i2 < 4; ++i2) {
            int i = lb * 64 + wave * 16 + lq * 4 + i2;
            s[((size_t)b * L1 + i) * L2 + nj * 16 + lane15] = acc2[nj][i2];
        }
}

// ---------------- softmax over dim=1 (L1): bf16 alpha straight into Xc[320..351]
__global__ __launch_bounds__(256) void softmax_col(const float* __restrict__ s,
                                                   const float* __restrict__ amask,
                                                   __hip_bfloat16* __restrict__ Xc) {
    __shared__ float red[256];
    __shared__ float cmax[8], cscale[8];
    int b = blockIdx.x, jh = blockIdx.y, t = threadIdx.x;
    int jl = t & 7, j = jh * 8 + jl, ii = t >> 3;
    const float* sb = s + (size_t)b * L1 * L2;
    float v[16];
    float m = -1e30f;
    #pragma unroll
    for (int q = 0; q < 16; ++q) {
        v[q] = sb[(size_t)(ii + q * 32) * L2 + j];
        m = fmaxf(m, v[q]);
    }
    red[t] = m;
    __syncthreads();
    if (t < 8) {
        float mm = red[t];
        for (int p = 1; p < 32; ++p) mm = fmaxf(mm, red[p * 8 + t]);
        cmax[t] = mm;
    }
    __syncthreads();
    float cm = cmax[jl];
    float sum = 0.f;
    #pragma unroll
    for (int q = 0; q < 16; ++q) {
        v[q] = expf(v[q] - cm);
        sum += v[q];
    }
    red[t] = sum;
    __syncthreads();
    if (t < 8) {
        float ss = 0.f;
        for (int p = 0; p < 32; ++p) ss += red[p * 8 + t];
        float mk = amask[b * L2 + jh * 8 + t];
        cscale[t] = mk / (mk * ss + 1e-10f);
    }
    __syncthreads();
    float sc = cscale[jl];
    #pragma unroll
    for (int q = 0; q < 16; ++q) {
        int row = ii + q * 32;
        Xc[((size_t)b * XROWS + 1 + row) * XW + 320 + j] = __float2bfloat16(v[q] * sc);
    }
}

// ---------------- conv (proven R14: round-7 schedule + T1 XCD swizzle, 16x16):
// 256-thr, cb-split blocks, per-kc A double-buffer via global_load_lds,
// B direct-global, role-XOR balance.
__global__ __launch_bounds__(256, 4) void conv_v7(
        const __hip_bfloat16* __restrict__ Xc,
        const __hip_bfloat16* __restrict__ Wp2,
        const __hip_bfloat16* __restrict__ Gt,
        const float* __restrict__ ctx_b,
        const float* __restrict__ gate_b,
        float* __restrict__ part) {
    __shared__ __align__(16) char lds[16 * EP_LD1 * 4];   // 16,640B; stage aliases front
    const int t = threadIdx.x, wave = t >> 6, lane = t & 63;
    const int lane15 = lane & 15, lq = lane >> 4;
    // nwg = 2048 = 8 * 256; wf = (flat%8)*256 + flat/8 (m204 bijective remap)
    const int flat = blockIdx.y * 16 + blockIdx.x;
    const int wf = (flat & 7) * 256 + (flat >> 3);
    const int b = wf >> 4;
    const int wx = wf & 15;
    const int lb = wx >> 1, cb = wx & 1;
    const int l0 = lb * 64;
    const int role = wave ^ ((wx & 1) << 1);

    f32x4 acc[4][4];
    #pragma unroll
    for (int m = 0; m < 4; ++m)
        #pragma unroll
        for (int n = 0; n < 4; ++n) acc[m][n] = (f32x4)0.f;

    const char* XcB = (const char*)Xc + ((size_t)b * XROWS + l0) * ROW_B;
    const char* bbase = (const char*)Wp2 + (size_t)(cb * 4 + role) * WAVE_WP_B + lane * 16;

    #define STAGE_A(kc_, buf_) do {                                              \
        char* Ab_ = lds + (buf_) * ABUF_B;                                       \
        _Pragma("unroll")                                                        \
        for (int i = 0; i < 2; ++i) {                                            \
            int chunk = (i * 4 + wave) * 64 + lane;                              \
            if (chunk < 264) {                                                   \
                int row_ = chunk >> 2, c_ = chunk & 3;                           \
                int sc_ = (c_ ^ ((row_ >> 1) & 3)) << 4;                         \
                gload_lds16(XcB + (size_t)row_ * ROW_B + (kc_) * 64 + sc_,       \
                            Ab_ + (i * 4 + wave) * 1024);                        \
            }                                                                    \
        }                                                                        \
    } while (0)

    STAGE_A(0, 0);
    __syncthreads();

    for (int kc = 0; kc < NKC; ++kc) {
        const int cbuf = kc & 1;
        if (kc < NKC - 1) STAGE_A(kc + 1, cbuf ^ 1);
        const char* Ab = lds + cbuf * ABUF_B;
        if (kc < 10) {
            #pragma unroll
            for (int tap = 0; tap < 3; ++tap) {
                bf16x8 bw[4];
                #pragma unroll
                for (int n = 0; n < 4; ++n)
                    bw[n] = *(const bf16x8*)(bbase + (size_t)((kc * 3 + tap) * 4 + n) * 1024);
                bf16x8 af[4];
                #pragma unroll
                for (int m = 0; m < 4; ++m) {
                    int row = m * 16 + lane15 + tap;
                    af[m] = *(const bf16x8*)(Ab + row * 64 + ((lq ^ ((row >> 1) & 3)) << 4));
                }
                #pragma unroll
                for (int m = 0; m < 4; ++m)
                    #pragma unroll
                    for (int n = 0; n < 4; ++n)
                        acc[m][n] = __builtin_amdgcn_mfma_f32_16x16x32_bf16(
                            af[m], bw[n], acc[m][n], 0, 0, 0);
            }
        } else if (role >= 2) {
            const char* GtB = (const char*)Gt + (size_t)b * 3 * (32 * 256 * 2);
            #pragma unroll
            for (int tap = 0; tap < 3; ++tap) {
                bf16x8 bw[4];
                #pragma unroll
                for (int n = 0; n < 4; ++n) {
                    #pragma unroll
                    for (int jj = 0; jj < 8; ++jj)
                        ((short*)&bw[n])[jj] = *(const short*)(GtB +
                            (size_t)tap * (32 * 256 * 2) +
                            (size_t)(lq * 8 + jj) * 512 +
                            (size_t)(cb * 128 + (role & 1) * 64 + n * 16 + lane15) * 2);
                }
                bf16x8 af[4];
                #pragma unroll
                for (int m = 0; m < 4; ++m) {
                    int row = m * 16 + lane15 + tap;
                    af[m] = *(const bf16x8*)(Ab + row * 64 + ((lq ^ ((row >> 1) & 3)) << 4));
                }
                #pragma unroll
                for (int m = 0; m < 4; ++m)
                    #pragma unroll
                    for (int n = 0; n < 4; ++n)
                        acc[m][n] = __builtin_amdgcn_mfma_f32_16x16x32_bf16(
                            af[m], bw[n], acc[m][n], 0, 0, 0);
            }
        }
        __syncthreads();
    }
    #undef STAGE_A

    const int c0 = cb * 128;
    const int cl = t & 127, rh = t >> 7;
    const float bs = ctx_b[c0 + cl];
    const float bg = gate_b[c0 + cl];
    float* ep = (float*)lds;
    float pm = -1e30f;
    for (int ms = 0; ms < 4; ++ms) {
        __syncthreads();
        #pragma unroll
        for (int n = 0; n < 4; ++n) {
            int col = (role << 6) + (n << 4) + lane15;
            #pragma unroll
            for (int i2 = 0; i2 < 4; ++i2)
                ep[(lq * 4 + i2) * EP_LD1 + col] = acc[ms][n][i2];
        }
        __syncthreads();
        #pragma unroll
        for (int rr = 0; rr < 8; ++rr) {
            int r = rh * 8 + rr;
            float sv = ep[r * EP_LD1 + cl] + bs;
            float gv = ep[r * EP_LD1 + 128 + cl] + bg;
            pm = fmaxf(pm, tanhf(sv) * fmaxf(gv, 0.f));
        }
    }
    __syncthreads();
    ep[t] = pm;
    __syncthreads();
    if (t < 128)
        part[((size_t)b * 8 + lb) * 256 + c0 + cl] = fmaxf(ep[t], ep[t + 128]);
}

// ---------------- final: max over 8 l-blocks + linear
__global__ __launch_bounds__(256) void finalize(const float* __restrict__ part,
                                                const float* __restrict__ lin_w,
                                                const float* __restrict__ lin_b,
                                                float* __restrict__ out) {
    __shared__ float pl[256];
    __shared__ float red[256];
    int b = blockIdx.x, t = threadIdx.x;
    float p = part[((size_t)b * 8) * 256 + t];
    for (int lb = 1; lb < 8; ++lb)
        p = fmaxf(p, part[((size_t)b * 8 + lb) * 256 + t]);
    pl[t] = p;
    __syncthreads();
    for (int n = 0; n < NCLASS; ++n) {
        red[t] = pl[t] * lin_w[n * NC + t];
        __syncthreads();
        for (int sft = 128; sft > 0; sft >>= 1) {
            if (t < sft) red[t] += red[t + sft];
            __syncthreads();
        }
        if (t == 0) out[b * NCLASS + n] = red[0] + lin_b[n];
        __syncthreads();
    }
}

extern "C" void kernel_launch(void* const* d_in, const int* in_sizes, int n_in,
                              void* d_out, int out_size, void* d_ws, size_t ws_size,
                              hipStream_t stream) {
    const int* cids = (const int*)d_in[0];
    const int* aids = (const int*)d_in[2];
    const float* amask = (const float*)d_in[3];
    const float* wordmat = (const float*)d_in[4];
    const float* Wm = (const float*)d_in[5];
    const float* ctx_w = (const float*)d_in[6];
    const float* ctx_b = (const float*)d_in[7];
    const float* gate_w = (const float*)d_in[8];
    const float* gate_b = (const float*)d_in[9];
    const float* lin_w = (const float*)d_in[10];
    const float* lin_b = (const float*)d_in[11];
    float* out = (float*)d_out;

    float* sbuf = (float*)d_ws;                                 // 2,097,152 f
    float* part = sbuf + 2097152;                               // 262,144 f
    __hip_bfloat16* aspb = (__hip_bfloat16*)(part + 262144);    // 1,310,720 bf16
    __hip_bfloat16* sybf = aspb + 1310720;                      // 1,310,720
    __hip_bfloat16* Wb   = sybf + 1310720;                      // 97,280
    __hip_bfloat16* Wp2  = Wb + WB_ELEMS;                       // 491,520
    __hip_bfloat16* Wg2  = Wp2 + WP2_ELEMS;                     // 245,760
    __hip_bfloat16* Gt   = Wg2 + WG2_ELEMS;                     // 3,145,728
    __hip_bfloat16* Xc   = Gt + GT_ELEMS;                       // 23,158,784

    prep_all<<<PREP_BLOCKS + XCAT_BLOCKS, 256, 0, stream>>>(
        ctx_w, gate_w, Wm, aids, cids, wordmat, Wp2, Wb, Wg2, aspb, sybf, Xc);
    asp_mfma<<<64 + BB * 3, 256, 0, stream>>>(aspb, Wb, Wg2, sybf, Gt);
    sxs_mfma<<<dim3(L1 / 64, BB), 256, 0, stream>>>(Xc, Wb, sybf, sbuf);
    softmax_col<<<dim3(BB, 4), 256, 0, stream>>>(sbuf, amask, Xc);
    conv_v7<<<dim3(16, BB), 256, 0, stream>>>(Xc, Wp2, Gt, ctx_b, gate_b, part);
    finalize<<<BB, 256, 0, stream>>>(part, lin_w, lin_b, out);
}